// Round 1
// baseline (431.558 us; speedup 1.0000x reference)
//
#include <hip/hip_runtime.h>
#include <hip/hip_bf16.h>

#define DEVI __device__ __forceinline__

typedef __bf16 bf16_t;
typedef __bf16 bf16x8 __attribute__((ext_vector_type(8)));
typedef float  f32x4  __attribute__((ext_vector_type(4)));
typedef unsigned short u16x4 __attribute__((ext_vector_type(4)));

typedef __attribute__((address_space(1))) unsigned int gas_u32;
typedef __attribute__((address_space(3))) unsigned int las_u32;

#define LOG2E 1.4426950408889634f

// async global->LDS, 16B per lane; lds dest = wave-uniform base + lane*16
DEVI void gload16(const void* g, void* l) {
  __builtin_amdgcn_global_load_lds((gas_u32*)g, (las_u32*)l, 16, 0, 0);
}

DEVI unsigned short bf16bits(float f) {
  bf16_t b = (bf16_t)f;
  return __builtin_bit_cast(unsigned short, b);
}

DEVI float rmax16(float v) {
  v = fmaxf(v, __shfl_xor(v, 1));
  v = fmaxf(v, __shfl_xor(v, 2));
  v = fmaxf(v, __shfl_xor(v, 4));
  v = fmaxf(v, __shfl_xor(v, 8));
  return v;
}
DEVI float rsum16(float v) {
  v += __shfl_xor(v, 1);
  v += __shfl_xor(v, 2);
  v += __shfl_xor(v, 4);
  v += __shfl_xor(v, 8);
  return v;
}

// ---------- scale reduction (deterministic two-stage, f64) ----------
__global__ __launch_bounds__(256) void k_abssum(const float* __restrict__ w, int n,
                                                double* __restrict__ partials) {
  __shared__ double sm[256];
  const int t = threadIdx.x;
  double acc = 0.0;
  for (int i = blockIdx.x * 256 + t; i < n; i += 256 * 256)
    acc += (double)fabsf(w[i]);
  sm[t] = acc;
  __syncthreads();
  #pragma unroll
  for (int s = 128; s > 0; s >>= 1) {
    if (t < s) sm[t] += sm[t + s];
    __syncthreads();
  }
  if (t == 0) partials[blockIdx.x] = sm[0];
}

__global__ __launch_bounds__(256) void k_reduce2(const double* __restrict__ partials,
                                                 double* __restrict__ outs) {
  __shared__ double sm[256];
  const int t = threadIdx.x;
  sm[t] = partials[blockIdx.x * 256 + t];
  __syncthreads();
  #pragma unroll
  for (int s = 128; s > 0; s >>= 1) {
    if (t < s) sm[t] += sm[t + s];
    __syncthreads();
  }
  if (t == 0) outs[blockIdx.x] = sm[0];
}

// ---------- ternary sign quantization: {-1,0,+1} stored as bf16 (exact) ----------
__global__ __launch_bounds__(256) void k_quant(const float* __restrict__ w,
                                               const double* __restrict__ sum, double invn,
                                               bf16_t* __restrict__ out) {
  const double s = (*sum) * invn + 1e-5;  // mean + EPS
  const int i = blockIdx.x * 256 + threadIdx.x;
  double tq = (double)w[i] / s;
  tq = fmin(fmax(tq, -1.0), 1.0);
  out[i] = (bf16_t)(float)rint(tq);  // rint = round-half-even, matches jnp.round
}

// ---------- x f32 -> bf16 ----------
__global__ __launch_bounds__(256) void k_tobf16(const float* __restrict__ x,
                                                bf16_t* __restrict__ y) {
  const int i = blockIdx.x * 256 + threadIdx.x;
  const float4 v = ((const float4*)x)[i];
  u16x4 pk = { bf16bits(v.x), bf16bits(v.y), bf16bits(v.z), bf16bits(v.w) };
  ((u16x4*)y)[i] = pk;
}

// ---------- GEMM: C[m][d] = sum_k A[m][k]*Bw[d][k]  (both K-contiguous) ----------
// 128x128 tile, BK=64, 4 waves (2x2), 16x16x32 bf16 MFMA.
// LDS linear, source-pre-swizzled; ds_read swizzle byte ^= ((row&7)<<4).
// MODE 0: epilogue scatters s*acc into Q ([bh][n][64], scaled s*0.125*log2e),
//         K ([bh][n][64], scaled s), V transposed ([bh][64][n], scaled s).
// MODE 1: epilogue writes f32 Out[m][d] = s*acc + bias[d].
template<int MODE>
__global__ __launch_bounds__(256) void k_gemm(
    const bf16_t* __restrict__ A, const bf16_t* __restrict__ Bw,
    const double* __restrict__ sumptr, double invn,
    bf16_t* __restrict__ Qb, bf16_t* __restrict__ Kb, bf16_t* __restrict__ VTb,
    const float* __restrict__ bias, float* __restrict__ Out)
{
  __shared__ bf16_t lA[128 * 64];
  __shared__ bf16_t lB[128 * 64];
  const int t = threadIdx.x, l = t & 63, w = t >> 6;
  const int m0 = blockIdx.y * 128, n0 = blockIdx.x * 128;
  const int wr = w >> 1, wc = w & 1;
  const int srow = l >> 3, scol = (l & 7) * 8;
  const int lq = l & 15, lh = l >> 4;
  f32x4 acc[4][4] = {};
  for (int k0 = 0; k0 < 768; k0 += 64) {
    __syncthreads();
    #pragma unroll
    for (int i = 0; i < 4; ++i) {
      const int c = i * 4 + w;
      const int row = c * 8 + srow;
      const int gcol = scol ^ ((row & 7) * 8);
      gload16(A + (size_t)(m0 + row) * 768 + k0 + gcol, &lA[c * 512]);
    }
    #pragma unroll
    for (int i = 0; i < 4; ++i) {
      const int c = i * 4 + w;
      const int row = c * 8 + srow;
      const int gcol = scol ^ ((row & 7) * 8);
      gload16(Bw + (size_t)(n0 + row) * 768 + k0 + gcol, &lB[c * 512]);
    }
    __syncthreads();
    #pragma unroll
    for (int kb = 0; kb < 2; ++kb) {
      const int kByte = (kb * 32 + lh * 8) * 2;
      bf16x8 af[4], bf[4];
      #pragma unroll
      for (int i = 0; i < 4; ++i) {
        const int row = wr * 64 + i * 16 + lq;
        af[i] = *(const bf16x8*)((const char*)lA + row * 128 + (kByte ^ ((row & 7) << 4)));
      }
      #pragma unroll
      for (int j = 0; j < 4; ++j) {
        const int row = wc * 64 + j * 16 + lq;
        bf[j] = *(const bf16x8*)((const char*)lB + row * 128 + (kByte ^ ((row & 7) << 4)));
      }
      #pragma unroll
      for (int i = 0; i < 4; ++i)
        #pragma unroll
        for (int j = 0; j < 4; ++j)
          acc[i][j] = __builtin_amdgcn_mfma_f32_16x16x32_bf16(af[i], bf[j], acc[i][j], 0, 0, 0);
    }
  }
  const float s = (float)((*sumptr) * invn);  // mean (no EPS here, matches ref wq scale)
  if (MODE == 0) {
    const int d0 = n0 + wc * 64;
    const int which = d0 / 768;  // uniform per wave: 0=Q, 1=K, 2=V
    if (which == 2) {
      #pragma unroll
      for (int j = 0; j < 4; ++j) {
        const int d = d0 + j * 16 + lq;
        const int h = (d >> 6) % 12, hd = d & 63;
        #pragma unroll
        for (int i = 0; i < 4; ++i) {
          const int mb = m0 + wr * 64 + i * 16 + lh * 4;
          const int b = mb >> 10, n = mb & 1023;
          u16x4 pk;
          #pragma unroll
          for (int r = 0; r < 4; ++r) pk[r] = bf16bits(acc[i][j][r] * s);
          *(u16x4*)(VTb + ((size_t)(b * 12 + h) * 64 + hd) * 1024 + n) = pk;
        }
      }
    } else {
      bf16_t* __restrict__ dst = (which == 0) ? Qb : Kb;
      const float sc = (which == 0) ? s * 0.125f * LOG2E : s;
      #pragma unroll
      for (int j = 0; j < 4; ++j) {
        const int d = d0 + j * 16 + lq;
        const int h = (d >> 6) % 12, hd = d & 63;
        #pragma unroll
        for (int i = 0; i < 4; ++i) {
          #pragma unroll
          for (int r = 0; r < 4; ++r) {
            const int m = m0 + wr * 64 + i * 16 + lh * 4 + r;
            const int b = m >> 10, n = m & 1023;
            dst[((size_t)(b * 12 + h) * 1024 + n) * 64 + hd] = (bf16_t)(acc[i][j][r] * sc);
          }
        }
      }
    }
  } else {
    #pragma unroll
    for (int j = 0; j < 4; ++j) {
      const int d = n0 + wc * 64 + j * 16 + lq;
      const float bv = bias[d];
      #pragma unroll
      for (int i = 0; i < 4; ++i) {
        #pragma unroll
        for (int r = 0; r < 4; ++r) {
          const int m = m0 + wr * 64 + i * 16 + lh * 4 + r;
          Out[(size_t)m * 768 + d] = acc[i][j][r] * s + bv;
        }
      }
    }
  }
}

// ---------- flash attention ----------
// Q pre-scaled by s*SCALE*log2e (so softmax is exp2-direct), K,V by s.
// Block: (qb, bh); 4 waves x 32 q-rows; KV tiles of 64.
__global__ __launch_bounds__(256) void k_attn(
    const bf16_t* __restrict__ Qb, const bf16_t* __restrict__ Kb,
    const bf16_t* __restrict__ VTb, bf16_t* __restrict__ Ob)
{
  __shared__ bf16_t lK[64 * 64];       // [kk][d] linear, src-pre-swizzled
  __shared__ bf16_t lV[64 * 64];       // V^T tile [d][kk] linear, src-pre-swizzled
  __shared__ bf16_t lP[4][32 * 64];    // per-wave P, swizzled writes/reads
  const int t = threadIdx.x, l = t & 63, w = t >> 6;
  const int bh = blockIdx.y, qb = blockIdx.x;
  const int lq = l & 15, lh = l >> 4;
  const int srow = l >> 3, scol = (l & 7) * 8;

  const size_t qoff = ((size_t)bh * 1024 + qb * 128 + w * 32) * 64;
  bf16x8 qf[2][2];
  #pragma unroll
  for (int i = 0; i < 2; ++i)
    #pragma unroll
    for (int kb = 0; kb < 2; ++kb)
      qf[i][kb] = *(const bf16x8*)(Qb + qoff + (size_t)(i * 16 + lq) * 64 + kb * 32 + lh * 8);

  f32x4 o[2][4] = {};
  float mrun[8], lrun[8];
  #pragma unroll
  for (int i = 0; i < 8; ++i) { mrun[i] = -1e30f; lrun[i] = 0.0f; }

  for (int kt = 0; kt < 16; ++kt) {
    const int nn0 = kt * 64;
    __syncthreads();
    #pragma unroll
    for (int i = 0; i < 2; ++i) {  // K tile: rows = kk
      const int c = i * 4 + w;
      const int row = c * 8 + srow;
      const int gcol = scol ^ ((row & 7) * 8);
      gload16(Kb + ((size_t)bh * 1024 + nn0 + row) * 64 + gcol, &lK[c * 512]);
    }
    #pragma unroll
    for (int i = 0; i < 2; ++i) {  // V^T tile: rows = d
      const int c = i * 4 + w;
      const int row = c * 8 + srow;
      const int gcol = scol ^ ((row & 7) * 8);
      gload16(VTb + ((size_t)bh * 64 + row) * 1024 + nn0 + gcol, &lV[c * 512]);
    }
    __syncthreads();

    // S = Q K^T (already in log2 domain)
    f32x4 sfr[2][4] = {};
    #pragma unroll
    for (int kb = 0; kb < 2; ++kb) {
      const int kByte = (kb * 32 + lh * 8) * 2;
      bf16x8 kf[4];
      #pragma unroll
      for (int cb = 0; cb < 4; ++cb) {
        const int row = cb * 16 + lq;
        kf[cb] = *(const bf16x8*)((const char*)lK + row * 128 + (kByte ^ ((row & 7) << 4)));
      }
      #pragma unroll
      for (int i = 0; i < 2; ++i)
        #pragma unroll
        for (int cb = 0; cb < 4; ++cb)
          sfr[i][cb] = __builtin_amdgcn_mfma_f32_16x16x32_bf16(qf[i][kb], kf[cb], sfr[i][cb], 0, 0, 0);
    }

    // online softmax (rows per lane: lh*4 + r within each 16-row block)
    float corr[8];
    float pvv[2][4][4];
    #pragma unroll
    for (int i = 0; i < 2; ++i) {
      #pragma unroll
      for (int r = 0; r < 4; ++r) {
        const int idx = i * 4 + r;
        float mt = fmaxf(fmaxf(sfr[i][0][r], sfr[i][1][r]), fmaxf(sfr[i][2][r], sfr[i][3][r]));
        mt = rmax16(mt);
        const float mo = mrun[idx];
        const float mn = fmaxf(mo, mt);
        const float c_ = exp2f(mo - mn);
        float ts = 0.0f;
        #pragma unroll
        for (int cb = 0; cb < 4; ++cb) {
          const float p = exp2f(sfr[i][cb][r] - mn);
          pvv[i][cb][r] = p;
          ts += p;
        }
        ts = rsum16(ts);
        lrun[idx] = lrun[idx] * c_ + ts;
        mrun[idx] = mn;
        corr[idx] = c_;
      }
    }
    #pragma unroll
    for (int i = 0; i < 2; ++i)
      #pragma unroll
      for (int dcb = 0; dcb < 4; ++dcb)
        #pragma unroll
        for (int r = 0; r < 4; ++r)
          o[i][dcb][r] *= corr[i * 4 + r];

    // P -> LDS (C-layout regs to A-layout tile), swizzled
    #pragma unroll
    for (int i = 0; i < 2; ++i)
      #pragma unroll
      for (int cb = 0; cb < 4; ++cb)
        #pragma unroll
        for (int r = 0; r < 4; ++r) {
          const int row = i * 16 + lh * 4 + r;
          const int colb = (cb * 16 + lq) * 2;
          *(bf16_t*)((char*)lP[w] + row * 128 + (colb ^ ((row & 7) << 4))) =
              (bf16_t)pvv[i][cb][r];
        }
    __syncthreads();

    // O += P V
    #pragma unroll
    for (int kb = 0; kb < 2; ++kb) {
      const int kByte = (kb * 32 + lh * 8) * 2;
      bf16x8 pf[2], vf[4];
      #pragma unroll
      for (int i = 0; i < 2; ++i) {
        const int row = i * 16 + lq;
        pf[i] = *(const bf16x8*)((const char*)lP[w] + row * 128 + (kByte ^ ((row & 7) << 4)));
      }
      #pragma unroll
      for (int dcb = 0; dcb < 4; ++dcb) {
        const int row = dcb * 16 + lq;
        vf[dcb] = *(const bf16x8*)((const char*)lV + row * 128 + (kByte ^ ((row & 7) << 4)));
      }
      #pragma unroll
      for (int i = 0; i < 2; ++i)
        #pragma unroll
        for (int dcb = 0; dcb < 4; ++dcb)
          o[i][dcb] = __builtin_amdgcn_mfma_f32_16x16x32_bf16(pf[i], vf[dcb], o[i][dcb], 0, 0, 0);
    }
  }

  // normalize + store [B][N][H*64] bf16
  const int b = bh / 12, h = bh % 12;
  float inv[8];
  #pragma unroll
  for (int i = 0; i < 8; ++i) inv[i] = 1.0f / lrun[i];
  #pragma unroll
  for (int i = 0; i < 2; ++i)
    #pragma unroll
    for (int dcb = 0; dcb < 4; ++dcb)
      #pragma unroll
      for (int r = 0; r < 4; ++r) {
        const float val = o[i][dcb][r] * inv[i * 4 + r];
        const int n = qb * 128 + w * 32 + i * 16 + lh * 4 + r;
        const int hd = dcb * 16 + lq;
        Ob[((size_t)(b * 1024 + n)) * 768 + h * 64 + hd] = (bf16_t)val;
      }
}

// ---------- launch ----------
extern "C" void kernel_launch(void* const* d_in, const int* in_sizes, int n_in,
                              void* d_out, int out_size, void* d_ws, size_t ws_size,
                              hipStream_t stream) {
  const float* x      = (const float*)d_in[0];   // [16,1024,768]
  const float* w_qkv  = (const float*)d_in[1];   // [2304,768]
  const float* w_proj = (const float*)d_in[2];   // [768,768]
  const float* b_proj = (const float*)d_in[3];   // [768]
  float* out = (float*)d_out;

  char* ws = (char*)d_ws;
  double* part  = (double*)ws;                    // 2*256 doubles
  double* scl   = (double*)(ws + 4096);           // 2 doubles
  bf16_t* xbf   = (bf16_t*)(ws + 4608);                               // 25165824 B
  bf16_t* wqs   = (bf16_t*)(ws + 4608 + 25165824);                    //  3538944 B
  bf16_t* wps   = (bf16_t*)(ws + 4608 + 25165824 + 3538944);          //  1179648 B
  bf16_t* qbuf  = (bf16_t*)(ws + 4608 + 25165824 + 3538944 + 1179648);
  bf16_t* kbuf  = qbuf + 12582912;
  bf16_t* vtbuf = kbuf + 12582912;
  bf16_t* aout  = xbf;  // x dead after GEMM1; alias attention output here

  k_abssum<<<256, 256, 0, stream>>>(w_qkv, 2304 * 768, part);
  k_abssum<<<256, 256, 0, stream>>>(w_proj, 768 * 768, part + 256);
  k_reduce2<<<2, 256, 0, stream>>>(part, scl);
  k_quant<<<6912, 256, 0, stream>>>(w_qkv, scl, 1.0 / 1769472.0, wqs);
  k_quant<<<2304, 256, 0, stream>>>(w_proj, scl + 1, 1.0 / 589824.0, wps);
  k_tobf16<<<12288, 256, 0, stream>>>(x, xbf);
  k_gemm<0><<<dim3(18, 128), 256, 0, stream>>>(xbf, wqs, scl, 1.0 / 1769472.0,
                                               qbuf, kbuf, vtbuf, nullptr, nullptr);
  k_attn<<<dim3(8, 192), 256, 0, stream>>>(qbuf, kbuf, vtbuf, aout);
  k_gemm<1><<<dim3(6, 128), 256, 0, stream>>>(aout, wps, scl + 1, 1.0 / 589824.0,
                                              nullptr, nullptr, nullptr, b_proj, out);
}

// Round 2
// 235.824 us; speedup vs baseline: 1.8300x; 1.8300x over previous
//
#include <hip/hip_runtime.h>
#include <hip/hip_bf16.h>

#define DEVI __device__ __forceinline__

typedef __bf16 bf16_t;
typedef __bf16 bf16x8 __attribute__((ext_vector_type(8)));
typedef float  f32x4  __attribute__((ext_vector_type(4)));
typedef float  f32x16 __attribute__((ext_vector_type(16)));
typedef unsigned short u16x4 __attribute__((ext_vector_type(4)));
typedef unsigned int   u32x4 __attribute__((ext_vector_type(4)));

typedef __attribute__((address_space(1))) unsigned int gas_u32;
typedef __attribute__((address_space(3))) unsigned int las_u32;

#define LOG2E 1.4426950408889634f

// async global->LDS, 16B per lane; lds dest = wave-uniform base + lane*16
DEVI void gload16(const void* g, void* l) {
  __builtin_amdgcn_global_load_lds((gas_u32*)g, (las_u32*)l, 16, 0, 0);
}

DEVI unsigned short bf16bits(float f) {
  bf16_t b = (bf16_t)f;
  return __builtin_bit_cast(unsigned short, b);
}

DEVI unsigned pk2(float a, float b) {  // [lo=a, hi=b] as 2x bf16
  return ((unsigned)bf16bits(b) << 16) | (unsigned)bf16bits(a);
}

// ---------- scale reduction (deterministic two-stage, f64) ----------
__global__ __launch_bounds__(256) void k_abssum(const float* __restrict__ w, int n,
                                                double* __restrict__ partials) {
  __shared__ double sm[256];
  const int t = threadIdx.x;
  double acc = 0.0;
  for (int i = blockIdx.x * 256 + t; i < n; i += 256 * 256)
    acc += (double)fabsf(w[i]);
  sm[t] = acc;
  __syncthreads();
  #pragma unroll
  for (int s = 128; s > 0; s >>= 1) {
    if (t < s) sm[t] += sm[t + s];
    __syncthreads();
  }
  if (t == 0) partials[blockIdx.x] = sm[0];
}

__global__ __launch_bounds__(256) void k_reduce2(const double* __restrict__ partials,
                                                 double* __restrict__ outs) {
  __shared__ double sm[256];
  const int t = threadIdx.x;
  sm[t] = partials[blockIdx.x * 256 + t];
  __syncthreads();
  #pragma unroll
  for (int s = 128; s > 0; s >>= 1) {
    if (t < s) sm[t] += sm[t + s];
    __syncthreads();
  }
  if (t == 0) outs[blockIdx.x] = sm[0];
}

// ---------- ternary sign quantization: {-1,0,+1} stored as bf16 (exact) ----------
__global__ __launch_bounds__(256) void k_quant(const float* __restrict__ w,
                                               const double* __restrict__ sum, double invn,
                                               bf16_t* __restrict__ out) {
  const double s = (*sum) * invn + 1e-5;  // mean + EPS
  const int i = blockIdx.x * 256 + threadIdx.x;
  double tq = (double)w[i] / s;
  tq = fmin(fmax(tq, -1.0), 1.0);
  out[i] = (bf16_t)(float)rint(tq);  // rint = round-half-even, matches jnp.round
}

// ---------- x f32 -> bf16 ----------
__global__ __launch_bounds__(256) void k_tobf16(const float* __restrict__ x,
                                                bf16_t* __restrict__ y) {
  const int i = blockIdx.x * 256 + threadIdx.x;
  const float4 v = ((const float4*)x)[i];
  u16x4 pk = { bf16bits(v.x), bf16bits(v.y), bf16bits(v.z), bf16bits(v.w) };
  ((u16x4*)y)[i] = pk;
}

// ---------- GEMM: C[m][d] = sum_k A[m][k]*Bw[d][k]  (both K-contiguous) ----------
// 128x128 tile, BK=64, 4 waves (2x2), 16x16x32 bf16 MFMA.
// LDS linear, source-pre-swizzled; ds_read swizzle byte ^= ((row&7)<<4).
template<int MODE>
__global__ __launch_bounds__(256) void k_gemm(
    const bf16_t* __restrict__ A, const bf16_t* __restrict__ Bw,
    const double* __restrict__ sumptr, double invn,
    bf16_t* __restrict__ Qb, bf16_t* __restrict__ Kb, bf16_t* __restrict__ VTb,
    const float* __restrict__ bias, float* __restrict__ Out)
{
  __shared__ bf16_t lA[128 * 64];
  __shared__ bf16_t lB[128 * 64];
  const int t = threadIdx.x, l = t & 63, w = t >> 6;
  const int m0 = blockIdx.y * 128, n0 = blockIdx.x * 128;
  const int wr = w >> 1, wc = w & 1;
  const int srow = l >> 3, scol = (l & 7) * 8;
  const int lq = l & 15, lh = l >> 4;
  f32x4 acc[4][4] = {};
  for (int k0 = 0; k0 < 768; k0 += 64) {
    __syncthreads();
    #pragma unroll
    for (int i = 0; i < 4; ++i) {
      const int c = i * 4 + w;
      const int row = c * 8 + srow;
      const int gcol = scol ^ ((row & 7) * 8);
      gload16(A + (size_t)(m0 + row) * 768 + k0 + gcol, &lA[c * 512]);
    }
    #pragma unroll
    for (int i = 0; i < 4; ++i) {
      const int c = i * 4 + w;
      const int row = c * 8 + srow;
      const int gcol = scol ^ ((row & 7) * 8);
      gload16(Bw + (size_t)(n0 + row) * 768 + k0 + gcol, &lB[c * 512]);
    }
    __syncthreads();
    #pragma unroll
    for (int kb = 0; kb < 2; ++kb) {
      const int kByte = (kb * 32 + lh * 8) * 2;
      bf16x8 af[4], bf[4];
      #pragma unroll
      for (int i = 0; i < 4; ++i) {
        const int row = wr * 64 + i * 16 + lq;
        af[i] = *(const bf16x8*)((const char*)lA + row * 128 + (kByte ^ ((row & 7) << 4)));
      }
      #pragma unroll
      for (int j = 0; j < 4; ++j) {
        const int row = wc * 64 + j * 16 + lq;
        bf[j] = *(const bf16x8*)((const char*)lB + row * 128 + (kByte ^ ((row & 7) << 4)));
      }
      #pragma unroll
      for (int i = 0; i < 4; ++i)
        #pragma unroll
        for (int j = 0; j < 4; ++j)
          acc[i][j] = __builtin_amdgcn_mfma_f32_16x16x32_bf16(af[i], bf[j], acc[i][j], 0, 0, 0);
    }
  }
  const float s = (float)((*sumptr) * invn);  // mean (no EPS here, matches ref wq scale)
  if (MODE == 0) {
    const int d0 = n0 + wc * 64;
    const int which = d0 / 768;  // uniform per wave: 0=Q, 1=K, 2=V
    if (which == 2) {
      #pragma unroll
      for (int j = 0; j < 4; ++j) {
        const int d = d0 + j * 16 + lq;
        const int h = (d >> 6) % 12, hd = d & 63;
        #pragma unroll
        for (int i = 0; i < 4; ++i) {
          const int mb = m0 + wr * 64 + i * 16 + lh * 4;
          const int b = mb >> 10, n = mb & 1023;
          u16x4 pk;
          #pragma unroll
          for (int r = 0; r < 4; ++r) pk[r] = bf16bits(acc[i][j][r] * s);
          *(u16x4*)(VTb + ((size_t)(b * 12 + h) * 64 + hd) * 1024 + n) = pk;
        }
      }
    } else {
      bf16_t* __restrict__ dst = (which == 0) ? Qb : Kb;
      const float sc = (which == 0) ? s * 0.125f * LOG2E : s;
      #pragma unroll
      for (int j = 0; j < 4; ++j) {
        const int d = d0 + j * 16 + lq;
        const int h = (d >> 6) % 12, hd = d & 63;
        #pragma unroll
        for (int i = 0; i < 4; ++i) {
          #pragma unroll
          for (int r = 0; r < 4; ++r) {
            const int m = m0 + wr * 64 + i * 16 + lh * 4 + r;
            const int b = m >> 10, n = m & 1023;
            dst[((size_t)(b * 12 + h) * 1024 + n) * 64 + hd] = (bf16_t)(acc[i][j][r] * sc);
          }
        }
      }
    }
  } else {
    #pragma unroll
    for (int j = 0; j < 4; ++j) {
      const int d = n0 + wc * 64 + j * 16 + lq;
      const float bv = bias[d];
      #pragma unroll
      for (int i = 0; i < 4; ++i) {
        #pragma unroll
        for (int r = 0; r < 4; ++r) {
          const int m = m0 + wr * 64 + i * 16 + lh * 4 + r;
          Out[(size_t)m * 768 + d] = acc[i][j][r] * s + bv;
        }
      }
    }
  }
}

// ---------- flash attention, swapped-QK^T 32x32x16 structure ----------
// Q pre-scaled by s*SCALE*log2e, K,V by s. Grid: x=bh (192, XCD-affine), y=qb (8).
// 4 warps x 32 q-rows; KV tiles of 64, double-buffered; softmax fully in-lane.
__global__ __launch_bounds__(256, 3) void k_attn(
    const bf16_t* __restrict__ Qb, const bf16_t* __restrict__ Kb,
    const bf16_t* __restrict__ VTb, bf16_t* __restrict__ Ob)
{
  __shared__ bf16_t smem[2][2][4096];  // [buf][K/VT][64x64], 32 KiB
  const int t = threadIdx.x, l = t & 63, w = t >> 6;
  const int bh = blockIdx.x, qb = blockIdx.y;
  const int lq = l & 31, hi = l >> 5;
  const int srow = l >> 3, scol = (l & 7) * 8;
  const int q0 = qb * 128 + w * 32;

  // Q fragments (B-operand): qf[ks] = Q[q0+lq][ks*16 + hi*8 .. +8]
  bf16x8 qf[4];
  #pragma unroll
  for (int ks = 0; ks < 4; ++ks)
    qf[ks] = *(const bf16x8*)(Qb + ((size_t)bh * 1024 + q0 + lq) * 64 + ks * 16 + hi * 8);

  f32x16 ot[2] = {};
  float mrun = -1e30f, lrun = 0.0f;

  auto stage = [&](int buf, int kt) {
    const int nn0 = kt * 64;
    #pragma unroll
    for (int i = 0; i < 2; ++i) {
      const int c = i * 4 + w;
      const int row = c * 8 + srow;
      const int gcol = scol ^ ((row & 7) * 8);
      gload16(Kb + ((size_t)bh * 1024 + nn0 + row) * 64 + gcol, &smem[buf][0][c * 512]);
      gload16(VTb + ((size_t)bh * 64 + row) * 1024 + nn0 + gcol, &smem[buf][1][c * 512]);
    }
  };

  stage(0, 0);
  __syncthreads();

  for (int kt = 0; kt < 16; ++kt) {
    const int cur = kt & 1;
    if (kt < 15) stage(cur ^ 1, kt + 1);
    const char* lK = (const char*)smem[cur][0];
    const char* lV = (const char*)smem[cur][1];

    // S^T[kk][q] = sum_d K[kk][d] Q[q][d]  (log2 domain)
    f32x16 st[2] = {};
    __builtin_amdgcn_s_setprio(1);
    #pragma unroll
    for (int kt2 = 0; kt2 < 2; ++kt2) {
      #pragma unroll
      for (int ks = 0; ks < 4; ++ks) {
        const int row = kt2 * 32 + lq;
        const bf16x8 kf =
            *(const bf16x8*)(lK + row * 128 + ((ks * 32 + hi * 16) ^ ((row & 7) << 4)));
        st[kt2] = __builtin_amdgcn_mfma_f32_32x32x16_bf16(kf, qf[ks], st[kt2], 0, 0, 0);
      }
    }
    __builtin_amdgcn_s_setprio(0);

    // in-lane row max over 32 kk, then cross-half swap
    float pmax = st[0][0];
    #pragma unroll
    for (int r = 1; r < 16; ++r) pmax = fmaxf(pmax, st[0][r]);
    #pragma unroll
    for (int r = 0; r < 16; ++r) pmax = fmaxf(pmax, st[1][r]);
    pmax = fmaxf(pmax, __shfl_xor(pmax, 32));

    // defer-max rescale (T13)
    if (__any(pmax > mrun + 8.0f)) {
      const float mn = fmaxf(mrun, pmax);
      const float corr = __builtin_amdgcn_exp2f(mrun - mn);
      lrun *= corr;
      #pragma unroll
      for (int dt = 0; dt < 2; ++dt)
        #pragma unroll
        for (int r = 0; r < 16; ++r) ot[dt][r] *= corr;
      mrun = mn;
    }

    // P = exp2(S^T - m); pack to bf16 A/B-frags via half-swap; PV
    float psum = 0.0f;
    __builtin_amdgcn_s_setprio(1);
    #pragma unroll
    for (int g = 0; g < 4; ++g) {
      const int tile = g >> 1, r0 = (g & 1) * 8;
      float p[8];
      #pragma unroll
      for (int e = 0; e < 8; ++e) {
        p[e] = __builtin_amdgcn_exp2f(st[tile][r0 + e] - mrun);
        psum += p[e];
      }
      const unsigned w0 = pk2(p[0], p[1]), w1 = pk2(p[2], p[3]);
      const unsigned w2 = pk2(p[4], p[5]), w3 = pk2(p[6], p[7]);
      const unsigned x0 = __shfl_xor(w0, 32), x1 = __shfl_xor(w1, 32);
      const unsigned x2 = __shfl_xor(w2, 32), x3 = __shfl_xor(w3, 32);
      const u32x4 fw = hi ? u32x4{x2, x3, w2, w3} : u32x4{w0, w1, x0, x1};
      const bf16x8 pf = __builtin_bit_cast(bf16x8, fw);
      #pragma unroll
      for (int dt = 0; dt < 2; ++dt) {
        const int row = dt * 32 + lq;
        const bf16x8 vf =
            *(const bf16x8*)(lV + row * 128 + ((g * 32 + hi * 16) ^ ((row & 7) << 4)));
        ot[dt] = __builtin_amdgcn_mfma_f32_32x32x16_bf16(vf, pf, ot[dt], 0, 0, 0);
      }
    }
    __builtin_amdgcn_s_setprio(0);
    psum += __shfl_xor(psum, 32);
    lrun += psum;

    __syncthreads();  // next-tile stage complete; all warps done reading cur
  }

  // epilogue: O^T regs -> per-warp LDS [32 q][64 d] (swizzled) -> coalesced stores
  __syncthreads();
  bf16_t* olds = (bf16_t*)smem + w * 2048;  // 4 KiB per warp
  const float inv = 1.0f / lrun;
  #pragma unroll
  for (int dt = 0; dt < 2; ++dt)
    #pragma unroll
    for (int rg = 0; rg < 4; ++rg) {
      u16x4 pk;
      #pragma unroll
      for (int e = 0; e < 4; ++e) pk[e] = bf16bits(ot[dt][rg * 4 + e] * inv);
      const int d = rg * 8 + hi * 4 + dt * 32;
      *(u16x4*)((char*)olds + ((lq * 128 + d * 2) ^ ((lq & 7) << 4))) = pk;
    }
  __syncthreads();
  const int b = bh / 12, h = bh % 12;
  #pragma unroll
  for (int i = 0; i < 8; ++i) {
    const int q = i * 4 + (l >> 4);
    const u16x4 v =
        *(const u16x4*)((const char*)olds + ((q * 128 + (l & 15) * 8) ^ ((q & 7) << 4)));
    *(u16x4*)(Ob + ((size_t)(b * 1024 + q0 + q)) * 768 + h * 64 + (l & 15) * 4) = v;
  }
}

// ---------- launch ----------
extern "C" void kernel_launch(void* const* d_in, const int* in_sizes, int n_in,
                              void* d_out, int out_size, void* d_ws, size_t ws_size,
                              hipStream_t stream) {
  const float* x      = (const float*)d_in[0];   // [16,1024,768]
  const float* w_qkv  = (const float*)d_in[1];   // [2304,768]
  const float* w_proj = (const float*)d_in[2];   // [768,768]
  const float* b_proj = (const float*)d_in[3];   // [768]
  float* out = (float*)d_out;

  char* ws = (char*)d_ws;
  double* part  = (double*)ws;                    // 2*256 doubles
  double* scl   = (double*)(ws + 4096);           // 2 doubles
  bf16_t* xbf   = (bf16_t*)(ws + 4608);                               // 25165824 B
  bf16_t* wqs   = (bf16_t*)(ws + 4608 + 25165824);                    //  3538944 B
  bf16_t* wps   = (bf16_t*)(ws + 4608 + 25165824 + 3538944);          //  1179648 B
  bf16_t* qbuf  = (bf16_t*)(ws + 4608 + 25165824 + 3538944 + 1179648);
  bf16_t* kbuf  = qbuf + 12582912;
  bf16_t* vtbuf = kbuf + 12582912;
  bf16_t* aout  = xbf;  // x dead after GEMM1; alias attention output here

  k_abssum<<<256, 256, 0, stream>>>(w_qkv, 2304 * 768, part);
  k_abssum<<<256, 256, 0, stream>>>(w_proj, 768 * 768, part + 256);
  k_reduce2<<<2, 256, 0, stream>>>(part, scl);
  k_quant<<<6912, 256, 0, stream>>>(w_qkv, scl, 1.0 / 1769472.0, wqs);
  k_quant<<<2304, 256, 0, stream>>>(w_proj, scl + 1, 1.0 / 589824.0, wps);
  k_tobf16<<<12288, 256, 0, stream>>>(x, xbf);
  k_gemm<0><<<dim3(18, 128), 256, 0, stream>>>(xbf, wqs, scl, 1.0 / 1769472.0,
                                               qbuf, kbuf, vtbuf, nullptr, nullptr);
  k_attn<<<dim3(192, 8), 256, 0, stream>>>(qbuf, kbuf, vtbuf, aout);
  k_gemm<1><<<dim3(6, 128), 256, 0, stream>>>(aout, wps, scl + 1, 1.0 / 589824.0,
                                              nullptr, nullptr, nullptr, b_proj, out);
}

// Round 4
// 230.605 us; speedup vs baseline: 1.8714x; 1.0226x over previous
//
#include <hip/hip_runtime.h>
#include <hip/hip_bf16.h>

#define DEVI __device__ __forceinline__

typedef __bf16 bf16_t;
typedef __bf16 bf16x8 __attribute__((ext_vector_type(8)));
typedef float  f32x4  __attribute__((ext_vector_type(4)));
typedef float  f32x16 __attribute__((ext_vector_type(16)));
typedef unsigned short u16x4 __attribute__((ext_vector_type(4)));
typedef unsigned int   u32x4 __attribute__((ext_vector_type(4)));

typedef __attribute__((address_space(1))) unsigned int gas_u32;
typedef __attribute__((address_space(3))) unsigned int las_u32;

#define LOG2E 1.4426950408889634f

// async global->LDS, 16B per lane; lds dest = wave-uniform base + lane*16
DEVI void gload16(const void* g, void* l) {
  __builtin_amdgcn_global_load_lds((gas_u32*)g, (las_u32*)l, 16, 0, 0);
}

DEVI unsigned short bf16bits(float f) {
  bf16_t b = (bf16_t)f;
  return __builtin_bit_cast(unsigned short, b);
}

DEVI unsigned pk2(float a, float b) {  // [lo=a, hi=b] as 2x bf16
  return ((unsigned)bf16bits(b) << 16) | (unsigned)bf16bits(a);
}

// ---------- scale reduction (deterministic two-stage, f64) ----------
__global__ __launch_bounds__(256) void k_abssum(const float* __restrict__ w, int n,
                                                double* __restrict__ partials) {
  __shared__ double sm[256];
  const int t = threadIdx.x;
  double acc = 0.0;
  for (int i = blockIdx.x * 256 + t; i < n; i += 256 * 256)
    acc += (double)fabsf(w[i]);
  sm[t] = acc;
  __syncthreads();
  #pragma unroll
  for (int s = 128; s > 0; s >>= 1) {
    if (t < s) sm[t] += sm[t + s];
    __syncthreads();
  }
  if (t == 0) partials[blockIdx.x] = sm[0];
}

__global__ __launch_bounds__(256) void k_reduce2(const double* __restrict__ partials,
                                                 double* __restrict__ outs) {
  __shared__ double sm[256];
  const int t = threadIdx.x;
  sm[t] = partials[blockIdx.x * 256 + t];
  __syncthreads();
  #pragma unroll
  for (int s = 128; s > 0; s >>= 1) {
    if (t < s) sm[t] += sm[t + s];
    __syncthreads();
  }
  if (t == 0) outs[blockIdx.x] = sm[0];
}

// ---------- ternary sign quantization: {-1,0,+1} stored as bf16 (exact) ----------
__global__ __launch_bounds__(256) void k_quant(const float* __restrict__ w,
                                               const double* __restrict__ sum, double invn,
                                               bf16_t* __restrict__ out) {
  const double s = (*sum) * invn + 1e-5;  // mean + EPS
  const int i = blockIdx.x * 256 + threadIdx.x;
  double tq = (double)w[i] / s;
  tq = fmin(fmax(tq, -1.0), 1.0);
  out[i] = (bf16_t)(float)rint(tq);  // rint = round-half-even, matches jnp.round
}

// ---------- x f32 -> bf16 ----------
__global__ __launch_bounds__(256) void k_tobf16(const float* __restrict__ x,
                                                bf16_t* __restrict__ y) {
  const int i = blockIdx.x * 256 + threadIdx.x;
  const float4 v = ((const float4*)x)[i];
  u16x4 pk = { bf16bits(v.x), bf16bits(v.y), bf16bits(v.z), bf16bits(v.w) };
  ((u16x4*)y)[i] = pk;
}

// ---------- GEMM: C[m][d] = sum_k A[m][k]*Bw[d][k]  (both K-contiguous) ----------
// 128x128 tile, BK=64, 4 waves (2x2), 16x16x32 bf16 MFMA.
// LDS linear, source-pre-swizzled; ds_read swizzle byte ^= ((row&7)<<4).
// Epilogues bounce each wave's 64x64 tile through its 8KB LDS quarter and
// store 16B/lane coalesced. __syncthreads() between staging writes and vector
// readback: required — scalar-typed ds_writes vs vector-typed ds_reads are
// TBAA-distinct and the scheduler may otherwise reorder them (round-3 bug).
template<int MODE>
__global__ __launch_bounds__(256) void k_gemm(
    const bf16_t* __restrict__ A, const bf16_t* __restrict__ Bw,
    const double* __restrict__ sumptr, double invn,
    bf16_t* __restrict__ Qb, bf16_t* __restrict__ Kb, bf16_t* __restrict__ VTb,
    const float* __restrict__ bias, float* __restrict__ Out,
    int nxblk)
{
  __shared__ bf16_t lds[2 * 128 * 64];
  bf16_t* lA = lds;
  bf16_t* lB = lds + 128 * 64;
  const int t = threadIdx.x, l = t & 63, w = t >> 6;

  // XCD-affine remap: each XCD gets a contiguous chunk of m-panels (A L2-resident)
  const int nblk = nxblk * 128;  // total blocks (multiple of 8)
  const int flat = blockIdx.y * nxblk + blockIdx.x;
  const int per = nblk >> 3;
  const int swz = (flat % 8) * per + flat / 8;
  const int m0 = (swz / nxblk) * 128, n0 = (swz % nxblk) * 128;

  const int wr = w >> 1, wc = w & 1;
  const int srow = l >> 3, scol = (l & 7) * 8;
  const int lq = l & 15, lh = l >> 4;
  f32x4 acc[4][4] = {};
  for (int k0 = 0; k0 < 768; k0 += 64) {
    __syncthreads();
    #pragma unroll
    for (int i = 0; i < 4; ++i) {
      const int c = i * 4 + w;
      const int row = c * 8 + srow;
      const int gcol = scol ^ ((row & 7) * 8);
      gload16(A + (size_t)(m0 + row) * 768 + k0 + gcol, &lA[c * 512]);
    }
    #pragma unroll
    for (int i = 0; i < 4; ++i) {
      const int c = i * 4 + w;
      const int row = c * 8 + srow;
      const int gcol = scol ^ ((row & 7) * 8);
      gload16(Bw + (size_t)(n0 + row) * 768 + k0 + gcol, &lB[c * 512]);
    }
    __syncthreads();
    #pragma unroll
    for (int kb = 0; kb < 2; ++kb) {
      const int kByte = (kb * 32 + lh * 8) * 2;
      bf16x8 af[4], bf[4];
      #pragma unroll
      for (int i = 0; i < 4; ++i) {
        const int row = wr * 64 + i * 16 + lq;
        af[i] = *(const bf16x8*)((const char*)lA + row * 128 + (kByte ^ ((row & 7) << 4)));
      }
      #pragma unroll
      for (int j = 0; j < 4; ++j) {
        const int row = wc * 64 + j * 16 + lq;
        bf[j] = *(const bf16x8*)((const char*)lB + row * 128 + (kByte ^ ((row & 7) << 4)));
      }
      #pragma unroll
      for (int i = 0; i < 4; ++i)
        #pragma unroll
        for (int j = 0; j < 4; ++j)
          acc[i][j] = __builtin_amdgcn_mfma_f32_16x16x32_bf16(af[i], bf[j], acc[i][j], 0, 0, 0);
    }
  }
  __syncthreads();  // all waves done reading lds before epilogue staging

  const float s = (float)((*sumptr) * invn);  // mean (no EPS here, matches ref wq scale)
  char* st = (char*)(lds + w * 4096);         // this wave's 8KB LDS quarter

  const int mrow0 = m0 + wr * 64;
  const int b = mrow0 >> 10, nbase = mrow0 & 1023;

  if (MODE == 0) {
    const int d0 = n0 + wc * 64;              // 64-aligned => exactly one head
    const int which = d0 / 768;               // uniform per wave: 0=Q, 1=K, 2=V
    const int hh = (d0 >> 6) % 12;
    // ---- staging writes (branch-divergent per wave) ----
    if (which == 2) {
      // stage transposed [hd][n]
      #pragma unroll
      for (int j = 0; j < 4; ++j)
        #pragma unroll
        for (int i = 0; i < 4; ++i)
          #pragma unroll
          for (int r = 0; r < 4; ++r) {
            const int rowd = j * 16 + lq;
            const int coln = (i * 16 + lh * 4 + r) * 2;
            *(bf16_t*)(st + rowd * 128 + (coln ^ ((rowd & 7) << 4))) =
                (bf16_t)(acc[i][j][r] * s);
          }
    } else {
      const float sc = (which == 0) ? s * 0.125f * LOG2E : s;
      // stage [n][d]
      #pragma unroll
      for (int i = 0; i < 4; ++i)
        #pragma unroll
        for (int j = 0; j < 4; ++j)
          #pragma unroll
          for (int r = 0; r < 4; ++r) {
            const int row = i * 16 + lh * 4 + r;
            const int colb = (j * 16 + lq) * 2;
            *(bf16_t*)(st + row * 128 + (colb ^ ((row & 7) << 4))) =
                (bf16_t)(acc[i][j][r] * sc);
          }
    }
    __syncthreads();  // order staging writes before vector readback
    // ---- vector readback + coalesced global stores ----
    if (which == 2) {
      char* dstp = (char*)(VTb + ((size_t)(b * 12 + hh) * 64) * 1024 + nbase);
      #pragma unroll
      for (int it = 0; it < 8; ++it) {
        const int rowd = it * 8 + (l >> 3);
        const int coln = (l & 7) * 16;
        const u32x4 v = *(const u32x4*)(st + rowd * 128 + (coln ^ ((rowd & 7) << 4)));
        *(u32x4*)(dstp + rowd * 2048 + coln) = v;
      }
    } else {
      bf16_t* __restrict__ dst = (which == 0) ? Qb : Kb;
      // wave tile is one contiguous 8KB block: [bh][nbase..nbase+63][0..63]
      char* dstp = (char*)(dst + ((size_t)(b * 12 + hh) * 1024 + nbase) * 64);
      #pragma unroll
      for (int it = 0; it < 8; ++it) {
        const int row = it * 8 + (l >> 3);
        const int colb = (l & 7) * 16;
        const u32x4 v = *(const u32x4*)(st + row * 128 + (colb ^ ((row & 7) << 4)));
        *(u32x4*)(dstp + row * 128 + colb) = v;
      }
    }
  } else {
    // f32 out, two 32-row chunks of 8KB each
    const int d0 = n0 + wc * 64;
    const float4 bv = *(const float4*)(bias + d0 + (l & 15) * 4);
    #pragma unroll
    for (int c = 0; c < 2; ++c) {
      #pragma unroll
      for (int i2 = 0; i2 < 2; ++i2) {
        const int i = c * 2 + i2;
        #pragma unroll
        for (int j = 0; j < 4; ++j)
          #pragma unroll
          for (int r = 0; r < 4; ++r) {
            const int row = i2 * 16 + lh * 4 + r;
            const int colb = (j * 16 + lq) * 4;
            *(float*)(st + row * 256 + (colb ^ ((row & 7) << 4))) = acc[i][j][r] * s;
          }
      }
      __syncthreads();  // staging writes -> readback ordering
      #pragma unroll
      for (int it = 0; it < 8; ++it) {
        const int row = it * 4 + (l >> 4);
        const int colb = (l & 15) * 16;
        float4 v = *(const float4*)(st + row * 256 + (colb ^ ((row & 7) << 4)));
        v.x += bv.x; v.y += bv.y; v.z += bv.z; v.w += bv.w;
        *(float4*)((char*)(Out + (size_t)(mrow0 + c * 32 + row) * 768 + d0) + colb) = v;
      }
      __syncthreads();  // chunk-0 reads done before chunk-1 overwrites
    }
  }
}

// ---------- flash attention, swapped-QK^T 32x32x16 structure ----------
// Q pre-scaled by s*SCALE*log2e, K,V by s. Grid: x=bh (192, XCD-affine), y=qb (8).
// 4 warps x 32 q-rows; KV tiles of 64, double-buffered; softmax fully in-lane.
__global__ __launch_bounds__(256, 3) void k_attn(
    const bf16_t* __restrict__ Qb, const bf16_t* __restrict__ Kb,
    const bf16_t* __restrict__ VTb, bf16_t* __restrict__ Ob)
{
  __shared__ bf16_t smem[2][2][4096];  // [buf][K/VT][64x64], 32 KiB
  const int t = threadIdx.x, l = t & 63, w = t >> 6;
  const int bh = blockIdx.x, qb = blockIdx.y;
  const int lq = l & 31, hi = l >> 5;
  const int srow = l >> 3, scol = (l & 7) * 8;
  const int q0 = qb * 128 + w * 32;

  // Q fragments (B-operand): qf[ks] = Q[q0+lq][ks*16 + hi*8 .. +8]
  bf16x8 qf[4];
  #pragma unroll
  for (int ks = 0; ks < 4; ++ks)
    qf[ks] = *(const bf16x8*)(Qb + ((size_t)bh * 1024 + q0 + lq) * 64 + ks * 16 + hi * 8);

  f32x16 ot[2] = {};
  float mrun = -1e30f, lrun = 0.0f;

  auto stage = [&](int buf, int kt) {
    const int nn0 = kt * 64;
    #pragma unroll
    for (int i = 0; i < 2; ++i) {
      const int c = i * 4 + w;
      const int row = c * 8 + srow;
      const int gcol = scol ^ ((row & 7) * 8);
      gload16(Kb + ((size_t)bh * 1024 + nn0 + row) * 64 + gcol, &smem[buf][0][c * 512]);
      gload16(VTb + ((size_t)bh * 64 + row) * 1024 + nn0 + gcol, &smem[buf][1][c * 512]);
    }
  };

  stage(0, 0);
  __syncthreads();

  for (int kt = 0; kt < 16; ++kt) {
    const int cur = kt & 1;
    if (kt < 15) stage(cur ^ 1, kt + 1);
    const char* lK = (const char*)smem[cur][0];
    const char* lV = (const char*)smem[cur][1];

    // S^T[kk][q] = sum_d K[kk][d] Q[q][d]  (log2 domain)
    f32x16 st[2] = {};
    __builtin_amdgcn_s_setprio(1);
    #pragma unroll
    for (int kt2 = 0; kt2 < 2; ++kt2) {
      #pragma unroll
      for (int ks = 0; ks < 4; ++ks) {
        const int row = kt2 * 32 + lq;
        const bf16x8 kf =
            *(const bf16x8*)(lK + row * 128 + ((ks * 32 + hi * 16) ^ ((row & 7) << 4)));
        st[kt2] = __builtin_amdgcn_mfma_f32_32x32x16_bf16(kf, qf[ks], st[kt2], 0, 0, 0);
      }
    }
    __builtin_amdgcn_s_setprio(0);

    // in-lane row max over 32 kk, then cross-half swap
    float pmax = st[0][0];
    #pragma unroll
    for (int r = 1; r < 16; ++r) pmax = fmaxf(pmax, st[0][r]);
    #pragma unroll
    for (int r = 0; r < 16; ++r) pmax = fmaxf(pmax, st[1][r]);
    pmax = fmaxf(pmax, __shfl_xor(pmax, 32));

    // defer-max rescale (T13)
    if (__any(pmax > mrun + 8.0f)) {
      const float mn = fmaxf(mrun, pmax);
      const float corr = __builtin_amdgcn_exp2f(mrun - mn);
      lrun *= corr;
      #pragma unroll
      for (int dt = 0; dt < 2; ++dt)
        #pragma unroll
        for (int r = 0; r < 16; ++r) ot[dt][r] *= corr;
      mrun = mn;
    }

    // P = exp2(S^T - m); pack to bf16 A/B-frags via half-swap; PV
    float psum = 0.0f;
    __builtin_amdgcn_s_setprio(1);
    #pragma unroll
    for (int g = 0; g < 4; ++g) {
      const int tile = g >> 1, r0 = (g & 1) * 8;
      float p[8];
      #pragma unroll
      for (int e = 0; e < 8; ++e) {
        p[e] = __builtin_amdgcn_exp2f(st[tile][r0 + e] - mrun);
        psum += p[e];
      }
      const unsigned w0 = pk2(p[0], p[1]), w1 = pk2(p[2], p[3]);
      const unsigned w2 = pk2(p[4], p[5]), w3 = pk2(p[6], p[7]);
      const unsigned x0 = __shfl_xor(w0, 32), x1 = __shfl_xor(w1, 32);
      const unsigned x2 = __shfl_xor(w2, 32), x3 = __shfl_xor(w3, 32);
      const u32x4 fw = hi ? u32x4{x2, x3, w2, w3} : u32x4{w0, w1, x0, x1};
      const bf16x8 pf = __builtin_bit_cast(bf16x8, fw);
      #pragma unroll
      for (int dt = 0; dt < 2; ++dt) {
        const int row = dt * 32 + lq;
        const bf16x8 vf =
            *(const bf16x8*)(lV + row * 128 + ((g * 32 + hi * 16) ^ ((row & 7) << 4)));
        ot[dt] = __builtin_amdgcn_mfma_f32_32x32x16_bf16(vf, pf, ot[dt], 0, 0, 0);
      }
    }
    __builtin_amdgcn_s_setprio(0);
    psum += __shfl_xor(psum, 32);
    lrun += psum;

    __syncthreads();  // next-tile stage complete; all warps done reading cur
  }

  // epilogue: O^T regs -> per-warp LDS [32 q][64 d] (swizzled) -> coalesced stores
  __syncthreads();
  bf16_t* olds = (bf16_t*)smem + w * 2048;  // 4 KiB per warp
  const float inv = 1.0f / lrun;
  #pragma unroll
  for (int dt = 0; dt < 2; ++dt)
    #pragma unroll
    for (int rg = 0; rg < 4; ++rg) {
      u16x4 pk;
      #pragma unroll
      for (int e = 0; e < 4; ++e) pk[e] = bf16bits(ot[dt][rg * 4 + e] * inv);
      const int d = rg * 8 + hi * 4 + dt * 32;
      *(u16x4*)((char*)olds + ((lq * 128 + d * 2) ^ ((lq & 7) << 4))) = pk;
    }
  __syncthreads();
  const int b = bh / 12, h = bh % 12;
  #pragma unroll
  for (int i = 0; i < 8; ++i) {
    const int q = i * 4 + (l >> 4);
    const u16x4 v =
        *(const u16x4*)((const char*)olds + ((q * 128 + (l & 15) * 8) ^ ((q & 7) << 4)));
    *(u16x4*)(Ob + ((size_t)(b * 1024 + q0 + q)) * 768 + h * 64 + (l & 15) * 4) = v;
  }
}

// ---------- launch ----------
extern "C" void kernel_launch(void* const* d_in, const int* in_sizes, int n_in,
                              void* d_out, int out_size, void* d_ws, size_t ws_size,
                              hipStream_t stream) {
  const float* x      = (const float*)d_in[0];   // [16,1024,768]
  const float* w_qkv  = (const float*)d_in[1];   // [2304,768]
  const float* w_proj = (const float*)d_in[2];   // [768,768]
  const float* b_proj = (const float*)d_in[3];   // [768]
  float* out = (float*)d_out;

  char* ws = (char*)d_ws;
  double* part  = (double*)ws;                    // 2*256 doubles
  double* scl   = (double*)(ws + 4096);           // 2 doubles
  bf16_t* xbf   = (bf16_t*)(ws + 4608);                               // 25165824 B
  bf16_t* wqs   = (bf16_t*)(ws + 4608 + 25165824);                    //  3538944 B
  bf16_t* wps   = (bf16_t*)(ws + 4608 + 25165824 + 3538944);          //  1179648 B
  bf16_t* qbuf  = (bf16_t*)(ws + 4608 + 25165824 + 3538944 + 1179648);
  bf16_t* kbuf  = qbuf + 12582912;
  bf16_t* vtbuf = kbuf + 12582912;
  bf16_t* aout  = xbf;  // x dead after GEMM1; alias attention output here

  k_abssum<<<256, 256, 0, stream>>>(w_qkv, 2304 * 768, part);
  k_abssum<<<256, 256, 0, stream>>>(w_proj, 768 * 768, part + 256);
  k_reduce2<<<2, 256, 0, stream>>>(part, scl);
  k_quant<<<6912, 256, 0, stream>>>(w_qkv, scl, 1.0 / 1769472.0, wqs);
  k_quant<<<2304, 256, 0, stream>>>(w_proj, scl + 1, 1.0 / 589824.0, wps);
  k_tobf16<<<12288, 256, 0, stream>>>(x, xbf);
  k_gemm<0><<<dim3(18, 128), 256, 0, stream>>>(xbf, wqs, scl, 1.0 / 1769472.0,
                                               qbuf, kbuf, vtbuf, nullptr, nullptr, 18);
  k_attn<<<dim3(192, 8), 256, 0, stream>>>(qbuf, kbuf, vtbuf, aout);
  k_gemm<1><<<dim3(6, 128), 256, 0, stream>>>(aout, wps, scl + 1, 1.0 / 589824.0,
                                              nullptr, nullptr, nullptr, b_proj, out, 6);
}

// Round 5
// 212.634 us; speedup vs baseline: 2.0296x; 1.0845x over previous
//
#include <hip/hip_runtime.h>
#include <hip/hip_bf16.h>

#define DEVI __device__ __forceinline__

typedef __bf16 bf16_t;
typedef __bf16 bf16x8 __attribute__((ext_vector_type(8)));
typedef float  f32x4  __attribute__((ext_vector_type(4)));
typedef float  f32x16 __attribute__((ext_vector_type(16)));
typedef unsigned short u16x4 __attribute__((ext_vector_type(4)));
typedef unsigned int   u32x4 __attribute__((ext_vector_type(4)));

typedef __attribute__((address_space(1))) unsigned int gas_u32;
typedef __attribute__((address_space(3))) unsigned int las_u32;

#define LOG2E 1.4426950408889634f

DEVI void gload16(const void* g, void* l) {
  __builtin_amdgcn_global_load_lds((gas_u32*)g, (las_u32*)l, 16, 0, 0);
}

DEVI unsigned short bf16bits(float f) {
  bf16_t b = (bf16_t)f;
  return __builtin_bit_cast(unsigned short, b);
}

DEVI unsigned pk2(float a, float b) {
  return ((unsigned)bf16bits(b) << 16) | (unsigned)bf16bits(a);
}

// ---------- scale reduction (deterministic two-stage, f64) ----------
__global__ __launch_bounds__(256) void k_abssum(const float* __restrict__ w, int n,
                                                double* __restrict__ partials) {
  __shared__ double sm[256];
  const int t = threadIdx.x;
  double acc = 0.0;
  for (int i = blockIdx.x * 256 + t; i < n; i += 256 * 256)
    acc += (double)fabsf(w[i]);
  sm[t] = acc;
  __syncthreads();
  #pragma unroll
  for (int s = 128; s > 0; s >>= 1) {
    if (t < s) sm[t] += sm[t + s];
    __syncthreads();
  }
  if (t == 0) partials[blockIdx.x] = sm[0];
}

__global__ __launch_bounds__(256) void k_reduce2(const double* __restrict__ partials,
                                                 double* __restrict__ outs) {
  __shared__ double sm[256];
  const int t = threadIdx.x;
  sm[t] = partials[blockIdx.x * 256 + t];
  __syncthreads();
  #pragma unroll
  for (int s = 128; s > 0; s >>= 1) {
    if (t < s) sm[t] += sm[t + s];
    __syncthreads();
  }
  if (t == 0) outs[blockIdx.x] = sm[0];
}

// ---------- ternary sign quantization ----------
__global__ __launch_bounds__(256) void k_quant(const float* __restrict__ w,
                                               const double* __restrict__ sum, double invn,
                                               bf16_t* __restrict__ out) {
  const double s = (*sum) * invn + 1e-5;
  const int i = blockIdx.x * 256 + threadIdx.x;
  double tq = (double)w[i] / s;
  tq = fmin(fmax(tq, -1.0), 1.0);
  out[i] = (bf16_t)(float)rint(tq);
}

// ---------- x f32 -> bf16 ----------
__global__ __launch_bounds__(256) void k_tobf16(const float* __restrict__ x,
                                                bf16_t* __restrict__ y) {
  const int i = blockIdx.x * 256 + threadIdx.x;
  const float4 v = ((const float4*)x)[i];
  u16x4 pk = { bf16bits(v.x), bf16bits(v.y), bf16bits(v.z), bf16bits(v.w) };
  ((u16x4*)y)[i] = pk;
}

// ---------- pipelined GEMM: C[m][d] = sum_k A[m][k]*Bw[d][k] ----------
// 256x128 tile, BK=64, 512 threads = 8 waves (4M x 2N, wave tile 64x64).
// 3 LDS slots (48KB each); stage kt+2 during kt; one counted vmcnt(6)/K-tile
// (T3+T4), raw s_barrier, setprio MFMA clusters (T5). Swizzle ^((row&7)<<4).
template<int MODE>
__global__ __launch_bounds__(512, 2) void k_gemm(
    const bf16_t* __restrict__ A, const bf16_t* __restrict__ Bw,
    const double* __restrict__ sumptr, double invn,
    bf16_t* __restrict__ Qb, bf16_t* __restrict__ Kb, bf16_t* __restrict__ VTb,
    const float* __restrict__ bias, float* __restrict__ Out,
    int nxblk)
{
  __shared__ __align__(16) char lds[147456];
  const int t = threadIdx.x, l = t & 63, w = t >> 6;

  const int nblk = nxblk * 64;
  const int flat = blockIdx.y * nxblk + blockIdx.x;
  const int per = nblk >> 3;
  const int swz = (flat & 7) * per + (flat >> 3);
  const int m0 = (swz / nxblk) * 256, n0 = (swz % nxblk) * 128;

  const int wm = w >> 1, wn = w & 1;
  const int srow = l >> 3, scol = (l & 7) * 8;
  const int lq = l & 15, lh = l >> 4;
  const int gcol = scol ^ (srow * 8);

  auto sA = [&](int slot, int kts, int ha, int c) {
    const int row = ha * 128 + (c * 8 + w) * 8 + srow;
    gload16(A + (size_t)(m0 + row) * 768 + kts * 64 + gcol,
            lds + slot * 49152 + ha * 16384 + (c * 8 + w) * 1024);
  };
  auto sB = [&](int slot, int kts, int c) {
    const int row = (c * 8 + w) * 8 + srow;
    gload16(Bw + (size_t)(n0 + row) * 768 + kts * 64 + gcol,
            lds + slot * 49152 + 32768 + (c * 8 + w) * 1024);
  };

  f32x4 acc[4][4] = {};

  sA(0, 0, 0, 0); sA(0, 0, 0, 1); sA(0, 0, 1, 0); sA(0, 0, 1, 1);
  sB(0, 0, 0);    sB(0, 0, 1);
  sA(1, 1, 0, 0); sA(1, 1, 0, 1); sA(1, 1, 1, 0); sA(1, 1, 1, 1);
  sB(1, 1, 0);    sB(1, 1, 1);
  asm volatile("s_waitcnt vmcnt(6)" ::: "memory");
  asm volatile("s_barrier" ::: "memory");

  #pragma unroll
  for (int kt = 0; kt < 12; ++kt) {
    const char* cA = lds + (kt % 3) * 49152;
    const char* cB = cA + 32768;
    const int st3 = (kt + 2) % 3;
    const bool stg = (kt < 10);

    // ---- phase A (kb = 0) ----
    {
      bf16x8 af[4], bf[4];
      #pragma unroll
      for (int i = 0; i < 4; ++i) {
        const int row = wm * 64 + i * 16 + lq;
        af[i] = *(const bf16x8*)(cA + row * 128 + ((lh * 16) ^ ((row & 7) << 4)));
      }
      #pragma unroll
      for (int j = 0; j < 4; ++j) {
        const int row = wn * 64 + j * 16 + lq;
        bf[j] = *(const bf16x8*)(cB + row * 128 + ((lh * 16) ^ ((row & 7) << 4)));
      }
      if (stg) { sA(st3, kt + 2, 0, 0); sA(st3, kt + 2, 0, 1); sB(st3, kt + 2, 0); }
      asm volatile("s_barrier" ::: "memory");
      __builtin_amdgcn_s_setprio(1);
      #pragma unroll
      for (int i = 0; i < 4; ++i)
        #pragma unroll
        for (int j = 0; j < 4; ++j)
          acc[i][j] = __builtin_amdgcn_mfma_f32_16x16x32_bf16(af[i], bf[j], acc[i][j], 0, 0, 0);
      __builtin_amdgcn_s_setprio(0);
      asm volatile("s_barrier" ::: "memory");
    }
    // ---- phase B (kb = 1) ----
    {
      bf16x8 af[4], bf[4];
      #pragma unroll
      for (int i = 0; i < 4; ++i) {
        const int row = wm * 64 + i * 16 + lq;
        af[i] = *(const bf16x8*)(cA + row * 128 + ((64 + lh * 16) ^ ((row & 7) << 4)));
      }
      #pragma unroll
      for (int j = 0; j < 4; ++j) {
        const int row = wn * 64 + j * 16 + lq;
        bf[j] = *(const bf16x8*)(cB + row * 128 + ((64 + lh * 16) ^ ((row & 7) << 4)));
      }
      if (stg) { sA(st3, kt + 2, 1, 0); sA(st3, kt + 2, 1, 1); sB(st3, kt + 2, 1); }
      asm volatile("s_barrier" ::: "memory");
      __builtin_amdgcn_s_setprio(1);
      #pragma unroll
      for (int i = 0; i < 4; ++i)
        #pragma unroll
        for (int j = 0; j < 4; ++j)
          acc[i][j] = __builtin_amdgcn_mfma_f32_16x16x32_bf16(af[i], bf[j], acc[i][j], 0, 0, 0);
      __builtin_amdgcn_s_setprio(0);
      if (stg) asm volatile("s_waitcnt vmcnt(6)" ::: "memory");
      else     asm volatile("s_waitcnt vmcnt(0)" ::: "memory");
      asm volatile("s_barrier" ::: "memory");
    }
  }

  // ---------------- epilogue ----------------
  const float s = (float)((*sumptr) * invn);
  char* st = lds + w * 8192;

  const int mrow0 = m0 + wm * 64;
  const int b = mrow0 >> 10, nbase = mrow0 & 1023;

  if (MODE == 0) {
    const int d0 = n0 + wn * 64;
    const int which = d0 / 768;
    const int hh = (d0 >> 6) % 12;
    if (which == 2) {
      #pragma unroll
      for (int j = 0; j < 4; ++j)
        #pragma unroll
        for (int i = 0; i < 4; ++i)
          #pragma unroll
          for (int r = 0; r < 4; ++r) {
            const int rowd = j * 16 + lq;
            const int coln = (i * 16 + lh * 4 + r) * 2;
            *(bf16_t*)(st + rowd * 128 + (coln ^ ((rowd & 7) << 4))) =
                (bf16_t)(acc[i][j][r] * s);
          }
    } else {
      const float sc = (which == 0) ? s * 0.125f * LOG2E : s;
      #pragma unroll
      for (int i = 0; i < 4; ++i)
        #pragma unroll
        for (int j = 0; j < 4; ++j)
          #pragma unroll
          for (int r = 0; r < 4; ++r) {
            const int row = i * 16 + lh * 4 + r;
            const int colb = (j * 16 + lq) * 2;
            *(bf16_t*)(st + row * 128 + (colb ^ ((row & 7) << 4))) =
                (bf16_t)(acc[i][j][r] * sc);
          }
    }
    __syncthreads();
    if (which == 2) {
      char* dstp = (char*)(VTb + ((size_t)(b * 12 + hh) * 64) * 1024 + nbase);
      #pragma unroll
      for (int it = 0; it < 8; ++it) {
        const int rowd = it * 8 + (l >> 3);
        const int coln = (l & 7) * 16;
        const u32x4 v = *(const u32x4*)(st + rowd * 128 + (coln ^ ((rowd & 7) << 4)));
        *(u32x4*)(dstp + rowd * 2048 + coln) = v;
      }
    } else {
      bf16_t* __restrict__ dst = (which == 0) ? Qb : Kb;
      char* dstp = (char*)(dst + ((size_t)(b * 12 + hh) * 1024 + nbase) * 64);
      #pragma unroll
      for (int it = 0; it < 8; ++it) {
        const int row = it * 8 + (l >> 3);
        const int colb = (l & 7) * 16;
        const u32x4 v = *(const u32x4*)(st + row * 128 + (colb ^ ((row & 7) << 4)));
        *(u32x4*)(dstp + row * 128 + colb) = v;
      }
    }
  } else {
    const int d0 = n0 + wn * 64;
    const float4 bv = *(const float4*)(bias + d0 + (l & 15) * 4);
    #pragma unroll
    for (int c = 0; c < 2; ++c) {
      #pragma unroll
      for (int i2 = 0; i2 < 2; ++i2) {
        const int i = c * 2 + i2;
        #pragma unroll
        for (int j = 0; j < 4; ++j)
          #pragma unroll
          for (int r = 0; r < 4; ++r) {
            const int row = i2 * 16 + lh * 4 + r;
            const int colb = (j * 16 + lq) * 4;
            *(float*)(st + row * 256 + (colb ^ ((row & 7) << 4))) = acc[i][j][r] * s;
          }
      }
      __syncthreads();
      #pragma unroll
      for (int it = 0; it < 8; ++it) {
        const int row = it * 4 + (l >> 4);
        const int colb = (l & 15) * 16;
        float4 v = *(const float4*)(st + row * 256 + (colb ^ ((row & 7) << 4)));
        v.x += bv.x; v.y += bv.y; v.z += bv.z; v.w += bv.w;
        *(float4*)((char*)(Out + (size_t)(mrow0 + c * 32 + row) * 768 + d0) + colb) = v;
      }
      __syncthreads();
    }
  }
}

// ---------- flash attention (unchanged, verified) ----------
__global__ __launch_bounds__(256, 3) void k_attn(
    const bf16_t* __restrict__ Qb, const bf16_t* __restrict__ Kb,
    const bf16_t* __restrict__ VTb, bf16_t* __restrict__ Ob)
{
  __shared__ bf16_t smem[2][2][4096];
  const int t = threadIdx.x, l = t & 63, w = t >> 6;
  const int bh = blockIdx.x, qb = blockIdx.y;
  const int lq = l & 31, hi = l >> 5;
  const int srow = l >> 3, scol = (l & 7) * 8;
  const int q0 = qb * 128 + w * 32;

  bf16x8 qf[4];
  #pragma unroll
  for (int ks = 0; ks < 4; ++ks)
    qf[ks] = *(const bf16x8*)(Qb + ((size_t)bh * 1024 + q0 + lq) * 64 + ks * 16 + hi * 8);

  f32x16 ot[2] = {};
  float mrun = -1e30f, lrun = 0.0f;

  auto stage = [&](int buf, int kt) {
    const int nn0 = kt * 64;
    #pragma unroll
    for (int i = 0; i < 2; ++i) {
      const int c = i * 4 + w;
      const int row = c * 8 + srow;
      const int gcol = scol ^ ((row & 7) * 8);
      gload16(Kb + ((size_t)bh * 1024 + nn0 + row) * 64 + gcol, &smem[buf][0][c * 512]);
      gload16(VTb + ((size_t)bh * 64 + row) * 1024 + nn0 + gcol, &smem[buf][1][c * 512]);
    }
  };

  stage(0, 0);
  __syncthreads();

  for (int kt = 0; kt < 16; ++kt) {
    const int cur = kt & 1;
    if (kt < 15) stage(cur ^ 1, kt + 1);
    const char* lK = (const char*)smem[cur][0];
    const char* lV = (const char*)smem[cur][1];

    f32x16 st[2] = {};
    __builtin_amdgcn_s_setprio(1);
    #pragma unroll
    for (int kt2 = 0; kt2 < 2; ++kt2) {
      #pragma unroll
      for (int ks = 0; ks < 4; ++ks) {
        const int row = kt2 * 32 + lq;
        const bf16x8 kf =
            *(const bf16x8*)(lK + row * 128 + ((ks * 32 + hi * 16) ^ ((row & 7) << 4)));
        st[kt2] = __builtin_amdgcn_mfma_f32_32x32x16_bf16(kf, qf[ks], st[kt2], 0, 0, 0);
      }
    }
    __builtin_amdgcn_s_setprio(0);

    float pmax = st[0][0];
    #pragma unroll
    for (int r = 1; r < 16; ++r) pmax = fmaxf(pmax, st[0][r]);
    #pragma unroll
    for (int r = 0; r < 16; ++r) pmax = fmaxf(pmax, st[1][r]);
    pmax = fmaxf(pmax, __shfl_xor(pmax, 32));

    if (__any(pmax > mrun + 8.0f)) {
      const float mn = fmaxf(mrun, pmax);
      const float corr = __builtin_amdgcn_exp2f(mrun - mn);
      lrun *= corr;
      #pragma unroll
      for (int dt = 0; dt < 2; ++dt)
        #pragma unroll
        for (int r = 0; r < 16; ++r) ot[dt][r] *= corr;
      mrun = mn;
    }

    float psum = 0.0f;
    __builtin_amdgcn_s_setprio(1);
    #pragma unroll
    for (int g = 0; g < 4; ++g) {
      const int tile = g >> 1, r0 = (g & 1) * 8;
      float p[8];
      #pragma unroll
      for (int e = 0; e < 8; ++e) {
        p[e] = __builtin_amdgcn_exp2f(st[tile][r0 + e] - mrun);
        psum += p[e];
      }
      const unsigned w0 = pk2(p[0], p[1]), w1 = pk2(p[2], p[3]);
      const unsigned w2 = pk2(p[4], p[5]), w3 = pk2(p[6], p[7]);
      const unsigned x0 = __shfl_xor(w0, 32), x1 = __shfl_xor(w1, 32);
      const unsigned x2 = __shfl_xor(w2, 32), x3 = __shfl_xor(w3, 32);
      const u32x4 fw = hi ? u32x4{x2, x3, w2, w3} : u32x4{w0, w1, x0, x1};
      const bf16x8 pf = __builtin_bit_cast(bf16x8, fw);
      #pragma unroll
      for (int dt = 0; dt < 2; ++dt) {
        const int row = dt * 32 + lq;
        const bf16x8 vf =
            *(const bf16x8*)(lV + row * 128 + ((g * 32 + hi * 16) ^ ((row & 7) << 4)));
        ot[dt] = __builtin_amdgcn_mfma_f32_32x32x16_bf16(vf, pf, ot[dt], 0, 0, 0);
      }
    }
    __builtin_amdgcn_s_setprio(0);
    psum += __shfl_xor(psum, 32);
    lrun += psum;

    __syncthreads();
  }

  __syncthreads();
  bf16_t* olds = (bf16_t*)smem + w * 2048;
  const float inv = 1.0f / lrun;
  #pragma unroll
  for (int dt = 0; dt < 2; ++dt)
    #pragma unroll
    for (int rg = 0; rg < 4; ++rg) {
      u16x4 pk;
      #pragma unroll
      for (int e = 0; e < 4; ++e) pk[e] = bf16bits(ot[dt][rg * 4 + e] * inv);
      const int d = rg * 8 + hi * 4 + dt * 32;
      *(u16x4*)((char*)olds + ((lq * 128 + d * 2) ^ ((lq & 7) << 4))) = pk;
    }
  __syncthreads();
  const int b = bh / 12, h = bh % 12;
  #pragma unroll
  for (int i = 0; i < 8; ++i) {
    const int q = i * 4 + (l >> 4);
    const u16x4 v =
        *(const u16x4*)((const char*)olds + ((q * 128 + (l & 15) * 8) ^ ((q & 7) << 4)));
    *(u16x4*)(Ob + ((size_t)(b * 1024 + q0 + q)) * 768 + h * 64 + (l & 15) * 4) = v;
  }
}

// ---------- launch ----------
extern "C" void kernel_launch(void* const* d_in, const int* in_sizes, int n_in,
                              void* d_out, int out_size, void* d_ws, size_t ws_size,
                              hipStream_t stream) {
  const float* x      = (const float*)d_in[0];
  const float* w_qkv  = (const float*)d_in[1];
  const float* w_proj = (const float*)d_in[2];
  const float* b_proj = (const float*)d_in[3];
  float* out = (float*)d_out;

  char* ws = (char*)d_ws;
  double* part  = (double*)ws;
  double* scl   = (double*)(ws + 4096);
  bf16_t* xbf   = (bf16_t*)(ws + 4608);
  bf16_t* wqs   = (bf16_t*)(ws + 4608 + 25165824);
  bf16_t* wps   = (bf16_t*)(ws + 4608 + 25165824 + 3538944);
  bf16_t* qbuf  = (bf16_t*)(ws + 4608 + 25165824 + 3538944 + 1179648);
  bf16_t* kbuf  = qbuf + 12582912;
  bf16_t* vtbuf = kbuf + 12582912;
  bf16_t* aout  = xbf;

  k_abssum<<<256, 256, 0, stream>>>(w_qkv, 2304 * 768, part);
  k_abssum<<<256, 256, 0, stream>>>(w_proj, 768 * 768, part + 256);
  k_reduce2<<<2, 256, 0, stream>>>(part, scl);
  k_quant<<<6912, 256, 0, stream>>>(w_qkv, scl, 1.0 / 1769472.0, wqs);
  k_quant<<<2304, 256, 0, stream>>>(w_proj, scl + 1, 1.0 / 589824.0, wps);
  k_tobf16<<<12288, 256, 0, stream>>>(x, xbf);
  k_gemm<0><<<dim3(18, 64), 512, 0, stream>>>(xbf, wqs, scl, 1.0 / 1769472.0,
                                              qbuf, kbuf, vtbuf, nullptr, nullptr, 18);
  k_attn<<<dim3(192, 8), 256, 0, stream>>>(qbuf, kbuf, vtbuf, aout);
  k_gemm<1><<<dim3(6, 64), 512, 0, stream>>>(aout, wps, scl + 1, 1.0 / 589824.0,
                                             nullptr, nullptr, nullptr, b_proj, out, 6);
}